// Round 1
// baseline (543.106 us; speedup 1.0000x reference)
//
#include <hip/hip_runtime.h>

typedef float   f32x4 __attribute__((ext_vector_type(4)));
typedef _Float16 f16x8 __attribute__((ext_vector_type(8)));

#define DEV static __device__ __forceinline__

// ---- problem constants ----
#define BB 4
#define TT 32
#define DD 768
#define SS 256          // Hp*Wp
#define NHD 12
#define HD 64
#define NSEQ  (BB*SS)   // 1024 sequences
#define MTOK  (NSEQ*TT) // 32768 tokens

DEV void async_copy16(const _Float16* g, _Float16* l) {
  __builtin_amdgcn_global_load_lds(
      (const __attribute__((address_space(1))) unsigned int*)g,
      (__attribute__((address_space(3))) unsigned int*)l,
      16, 0, 0);
}

// XOR-swizzled LDS 16B-chunk index for [rows][4 chunk] tiles (BK=32 f16).
DEV int swz_chunk(int r, int kc) {
  return r * 4 + (kc ^ (r & 3) ^ ((r >> 2) & 3));
}

// ---------------------------------------------------------------------------
// K0a: h (B,T,D,Hp,Wp) fp32 -> A[token][d] f16  (d<->s transpose via LDS)
// ---------------------------------------------------------------------------
__global__ __launch_bounds__(256) void k_transpose_h(const float* __restrict__ h,
                                                     _Float16* __restrict__ A) {
  __shared__ _Float16 Tl[256 * 65];
  const int slab = blockIdx.x;
  const int d0   = blockIdx.y * 64;
  const int t    = threadIdx.x;
  const float4* hv = (const float4*)(h + (slab * DD + d0) * SS);
  #pragma unroll
  for (int i = 0; i < 16; ++i) {
    int dd = i * 4 + (t >> 6);
    int s4 = (t & 63) * 4;
    float4 v = hv[dd * 64 + (t & 63)];
    Tl[(s4 + 0) * 65 + dd] = (_Float16)v.x;
    Tl[(s4 + 1) * 65 + dd] = (_Float16)v.y;
    Tl[(s4 + 2) * 65 + dd] = (_Float16)v.z;
    Tl[(s4 + 3) * 65 + dd] = (_Float16)v.w;
  }
  __syncthreads();
  #pragma unroll
  for (int p = 0; p < 8; ++p) {
    int s  = p * 32 + (t >> 3);
    int dd = (t & 7) * 8;
    f16x8 val;
    #pragma unroll
    for (int j = 0; j < 8; ++j) val[j] = Tl[s * 65 + dd + j];
    *(f16x8*)(A + (slab * SS + s) * DD + d0 + dd) = val;
  }
}

// ---------------------------------------------------------------------------
// K0b: weights fp32 -> f16
// ---------------------------------------------------------------------------
__global__ __launch_bounds__(256) void k_convert_w(const float* __restrict__ Wq,
                                                   const float* __restrict__ Wk,
                                                   const float* __restrict__ Wv,
                                                   const float* __restrict__ Wo,
                                                   _Float16* __restrict__ WQKV,
                                                   _Float16* __restrict__ WoH) {
  int idx = blockIdx.x * 256 + threadIdx.x;
  int row = idx / 96;
  int c8  = (idx % 96) * 8;
  const float* src; _Float16* dst;
  if (row < 768)       { src = Wq + row * 768;          dst = WQKV + row * 768; }
  else if (row < 1536) { src = Wk + (row - 768) * 768;  dst = WQKV + row * 768; }
  else if (row < 2304) { src = Wv + (row - 1536) * 768; dst = WQKV + row * 768; }
  else                 { src = Wo + (row - 2304) * 768; dst = WoH  + (row - 2304) * 768; }
  float4 v0 = *(const float4*)(src + c8);
  float4 v1 = *(const float4*)(src + c8 + 4);
  f16x8 o;
  o[0]=(_Float16)v0.x; o[1]=(_Float16)v0.y; o[2]=(_Float16)v0.z; o[3]=(_Float16)v0.w;
  o[4]=(_Float16)v1.x; o[5]=(_Float16)v1.y; o[6]=(_Float16)v1.z; o[7]=(_Float16)v1.w;
  *(f16x8*)(dst + c8) = o;
}

// ---------------------------------------------------------------------------
// K1: u_pen[(b*256+s)*32 + t] = lam * mean_d u
// ---------------------------------------------------------------------------
__global__ __launch_bounds__(256) void k_upen(const float* __restrict__ u,
                                              const float* __restrict__ lam,
                                              float* __restrict__ upen) {
  int slab = blockIdx.x >> 2;
  int q    = blockIdx.x & 3;
  int s    = threadIdx.x;
  const float* base = u + (slab * DD + q * 192) * SS + s;
  float sum = 0.f;
  for (int d = 0; d < 192; ++d) sum += base[d * SS];
  int b = slab >> 5, tt = slab & 31;
  float l = lam[slab * SS + s];
  atomicAdd(&upen[(b * SS + s) * TT + tt], sum * l * (1.0f / 768.0f));
}

// ---------------------------------------------------------------------------
// K2: QKV GEMM.  Block tile 128m x 256n, BK=32, 4 waves of 64x128.
// v3: double-buffered LDS, prefetch of K-tile t+1 issued BEFORE compute of
// tile t (T3 minimum 2-phase). One barrier per K-step; its implicit
// vmcnt(0) drain waits on loads that had the whole MFMA phase to land.
// Epilogue writes packed Qp/Kp/Vp[seq][head][t][hd], Q scaled by 1/8.
// mt-fastest: same-mt blocks share an XCD -> A-tile fetched once per XCD.
// ---------------------------------------------------------------------------
__global__ __launch_bounds__(256, 2) void k_gemm_qkv(const _Float16* __restrict__ A,
                                                     const _Float16* __restrict__ Bw,
                                                     const float* __restrict__ bq,
                                                     const float* __restrict__ bk,
                                                     const float* __restrict__ bv,
                                                     _Float16* __restrict__ Qp,
                                                     _Float16* __restrict__ Kp,
                                                     _Float16* __restrict__ Vp) {
  __shared__ _Float16 As[2][128 * 32];   // 512 chunks per buf
  __shared__ _Float16 Bs[2][256 * 32];   // 1024 chunks per buf
  const int mt = blockIdx.x & 255, nt = blockIdx.x >> 8;   // mt-fastest
  const int m0 = mt * 128, n0 = nt * 256;
  const int tid = threadIdx.x, w = tid >> 6, lane = tid & 63;
  const int wr = (w >> 1) * 64, wcc = (w & 1) * 128;
  f32x4 acc[4][8] = {};

  auto stage = [&](int buf, int k0) {
    #pragma unroll
    for (int i = 0; i < 2; ++i) {      // A: 512 chunks
      int c = tid + 256 * i;
      int row = c >> 2;
      int coff = ((c & 3) ^ (row & 3) ^ ((row >> 2) & 3)) * 8;
      async_copy16(A + (m0 + row) * DD + k0 + coff,
                   (_Float16*)((char*)&As[buf][0] + tid * 16 + i * 4096));
    }
    #pragma unroll
    for (int i = 0; i < 4; ++i) {      // B: 1024 chunks
      int c = tid + 256 * i;
      int row = c >> 2;
      int coff = ((c & 3) ^ (row & 3) ^ ((row >> 2) & 3)) * 8;
      async_copy16(Bw + (n0 + row) * DD + k0 + coff,
                   (_Float16*)((char*)&Bs[buf][0] + tid * 16 + i * 4096));
    }
  };

  stage(0, 0);
  __syncthreads();                     // drains vmcnt(0): buf0 ready
  for (int it = 0; it < 24; ++it) {
    const int cur = it & 1;
    if (it < 23) stage(cur ^ 1, (it + 1) * 32);   // issue next tile early
    const _Float16* Ac = &As[cur][0];
    const _Float16* Bc = &Bs[cur][0];
    f16x8 af[4], bf[8];
    #pragma unroll
    for (int mi = 0; mi < 4; ++mi)
      af[mi] = *(const f16x8*)&Ac[swz_chunk(wr + mi * 16 + (lane & 15), lane >> 4) * 8];
    #pragma unroll
    for (int ni = 0; ni < 8; ++ni)
      bf[ni] = *(const f16x8*)&Bc[swz_chunk(wcc + ni * 16 + (lane & 15), lane >> 4) * 8];
    #pragma unroll
    for (int mi = 0; mi < 4; ++mi)
      #pragma unroll
      for (int ni = 0; ni < 8; ++ni)
        acc[mi][ni] = __builtin_amdgcn_mfma_f32_16x16x32_f16(af[mi], bf[ni], acc[mi][ni], 0, 0, 0);
    __syncthreads();                   // waits prefetch (overlapped w/ compute)
  }
  // epilogue: n -> (sel, head, hd); m -> (b, t, s);  write packed [seq][head][t][hd]
  const int sel = nt / 3;                                   // 0=Q 1=K 2=V (block-uniform)
  const float scale = (sel == 0) ? 0.125f : 1.0f;           // fold 1/sqrt(64) into Q
  const float* bias = (sel == 0) ? bq : ((sel == 1) ? bk : bv);
  _Float16* dst = (sel == 0) ? Qp : ((sel == 1) ? Kp : Vp);
  const int slab = mt >> 1, s0 = (mt & 1) * 128;
  const int b = slab >> 5, t = slab & 31;
  #pragma unroll
  for (int ni = 0; ni < 8; ++ni) {
    int n768 = nt * 256 - sel * 768 + wcc + ni * 16 + (lane & 15);
    int head = n768 >> 6, hd = n768 & 63;
    float bs = bias[n768];
    long hb = (long)head * 2048 + t * 64 + hd;
    #pragma unroll
    for (int mi = 0; mi < 4; ++mi) {
      f32x4 v = acc[mi][ni];
      #pragma unroll
      for (int r = 0; r < 4; ++r) {
        int s = s0 + wr + mi * 16 + (lane >> 4) * 4 + r;
        long seq = b * 256 + s;
        dst[seq * 24576 + hb] = (_Float16)((v[r] + bs) * scale);
      }
    }
  }
}

// ---------------------------------------------------------------------------
// K3: attention v2. 1 wave per (seq, head); all global reads dense 4KB blocks.
// V transposed through per-wave LDS (stride 66: both sides 2-way = free).
// O written token-major into Abuf for the output GEMM.
// ---------------------------------------------------------------------------
__global__ __launch_bounds__(256) void k_attn(const _Float16* __restrict__ Qp,
                                              const _Float16* __restrict__ Kp,
                                              const _Float16* __restrict__ Vp,
                                              const float* __restrict__ upen,
                                              _Float16* __restrict__ O) {
  __shared__ _Float16 lds[4][32 * 66 + 32 * 40];   // per-wave: Vs[32][66], Ps[32][40]
  const int w = threadIdx.x >> 6, lane = threadIdx.x & 63;
  const int seq = blockIdx.x / 3, hg = blockIdx.x % 3;
  const int head = hg * 4 + w;
  const int b = seq >> 8, s = seq & 255;
  _Float16* Vs = &lds[w][0];
  _Float16* Ps = &lds[w][32 * 66];
  const long base = (long)(seq * NHD + head) * 2048;
  const _Float16* Qb = Qp + base;
  const _Float16* Kb = Kp + base;
  const _Float16* Vb = Vp + base;

  // stage V (dense 4KB) -> LDS stride 66, f16x2 writes (2-way, free)
  {
    int t = lane & 31, hh = (lane >> 5) * 32;
    f16x8 vc[4];
    #pragma unroll
    for (int c = 0; c < 4; ++c) vc[c] = *(const f16x8*)(Vb + t * 64 + hh + c * 8);
    #pragma unroll
    for (int c = 0; c < 4; ++c)
      #pragma unroll
      for (int p = 0; p < 4; ++p) {
        union { _Float16 h[2]; unsigned u; } pk;
        pk.h[0] = vc[c][2 * p]; pk.h[1] = vc[c][2 * p + 1];
        *(unsigned*)&Vs[t * 66 + hh + c * 8 + 2 * p] = pk.u;
      }
  }
  // Q/K fragments direct from global (dense within the 4KB block)
  f16x8 qf[2][2], kf[2][2];
  #pragma unroll
  for (int i = 0; i < 2; ++i)
    #pragma unroll
    for (int ks = 0; ks < 2; ++ks) {
      int off = (i * 16 + (lane & 15)) * 64 + ks * 32 + (lane >> 4) * 8;
      qf[i][ks] = *(const f16x8*)(Qb + off);
      kf[i][ks] = *(const f16x8*)(Kb + off);
    }
  // scores = (Q/8) . K^T
  f32x4 sc[2][2] = {};
  #pragma unroll
  for (int mq = 0; mq < 2; ++mq)
    #pragma unroll
    for (int nk = 0; nk < 2; ++nk)
      #pragma unroll
      for (int ks = 0; ks < 2; ++ks)
        sc[mq][nk] = __builtin_amdgcn_mfma_f32_16x16x32_f16(qf[mq][ks], kf[nk][ks], sc[mq][nk], 0, 0, 0);

  const float up0 = upen[seq * TT + (lane & 15)];
  const float up1 = upen[seq * TT + 16 + (lane & 15)];

  // softmax over 32 keys per query row
  #pragma unroll
  for (int mq = 0; mq < 2; ++mq) {
    #pragma unroll
    for (int r = 0; r < 4; ++r) {
      float s0 = sc[mq][0][r] - up0;
      float s1 = sc[mq][1][r] - up1;
      float mx = fmaxf(s0, s1);
      #pragma unroll
      for (int off = 1; off < 16; off <<= 1) mx = fmaxf(mx, __shfl_xor(mx, off, 64));
      float e0 = __expf(s0 - mx), e1 = __expf(s1 - mx);
      float sum = e0 + e1;
      #pragma unroll
      for (int off = 1; off < 16; off <<= 1) sum += __shfl_xor(sum, off, 64);
      float inv = 1.0f / sum;
      int row = mq * 16 + (lane >> 4) * 4 + r;
      Ps[row * 40 + (lane & 15)]      = (_Float16)(e0 * inv);
      Ps[row * 40 + 16 + (lane & 15)] = (_Float16)(e1 * inv);
    }
  }
  // PV
  f16x8 pf[2];
  #pragma unroll
  for (int mq = 0; mq < 2; ++mq)
    pf[mq] = *(const f16x8*)(Ps + (mq * 16 + (lane & 15)) * 40 + (lane >> 4) * 8);
  f32x4 oacc[2][4] = {};
  #pragma unroll
  for (int nh = 0; nh < 4; ++nh) {
    int hd = nh * 16 + (lane & 15);
    f16x8 vf;
    #pragma unroll
    for (int j = 0; j < 8; ++j) vf[j] = Vs[((lane >> 4) * 8 + j) * 66 + hd];  // 2-way, free
    #pragma unroll
    for (int mq = 0; mq < 2; ++mq)
      oacc[mq][nh] = __builtin_amdgcn_mfma_f32_16x16x32_f16(pf[mq], vf, oacc[mq][nh], 0, 0, 0);
  }
  // write O token-major [m][768]
  #pragma unroll
  for (int mq = 0; mq < 2; ++mq)
    #pragma unroll
    for (int nh = 0; nh < 4; ++nh) {
      int hd = nh * 16 + (lane & 15);
      #pragma unroll
      for (int r = 0; r < 4; ++r) {
        int t = mq * 16 + (lane >> 4) * 4 + r;
        O[((long)((b << 5) + t) * SS + s) * DD + head * HD + hd] = (_Float16)oacc[mq][nh][r];
      }
    }
}

// ---------------------------------------------------------------------------
// K4: output GEMM, swapped operands: C'[R][token] = Wo[R][:] . O[token][:]
// Block tile 128R x 256tok, 4 waves of 64x128. ct-fastest for XCD locality.
// v3: same double-buffered prefetch structure as K2.
// Writes final (B,T,D,Hp,Wp) fp32 with s-contiguous coalesced stores.
// ---------------------------------------------------------------------------
__global__ __launch_bounds__(256, 2) void k_gemm_out(const _Float16* __restrict__ Wn,
                                                     const _Float16* __restrict__ O,
                                                     const float* __restrict__ bo,
                                                     float* __restrict__ out) {
  __shared__ _Float16 As[2][128 * 32];   // Wo rows
  __shared__ _Float16 Bs[2][256 * 32];   // O token rows
  const int ct = blockIdx.x & 127, rt = blockIdx.x >> 7;   // ct-fastest
  const int R0 = rt * 128, C0 = ct * 256;
  const int tid = threadIdx.x, w = tid >> 6, lane = tid & 63;
  const int wr = (w >> 1) * 64, wcc = (w & 1) * 128;
  f32x4 acc[4][8] = {};

  auto stage = [&](int buf, int k0) {
    #pragma unroll
    for (int i = 0; i < 2; ++i) {
      int c = tid + 256 * i;
      int row = c >> 2;
      int coff = ((c & 3) ^ (row & 3) ^ ((row >> 2) & 3)) * 8;
      async_copy16(Wn + (R0 + row) * DD + k0 + coff,
                   (_Float16*)((char*)&As[buf][0] + tid * 16 + i * 4096));
    }
    #pragma unroll
    for (int i = 0; i < 4; ++i) {
      int c = tid + 256 * i;
      int row = c >> 2;
      int coff = ((c & 3) ^ (row & 3) ^ ((row >> 2) & 3)) * 8;
      async_copy16(O + (C0 + row) * DD + k0 + coff,
                   (_Float16*)((char*)&Bs[buf][0] + tid * 16 + i * 4096));
    }
  };

  stage(0, 0);
  __syncthreads();
  for (int it = 0; it < 24; ++it) {
    const int cur = it & 1;
    if (it < 23) stage(cur ^ 1, (it + 1) * 32);
    const _Float16* Ac = &As[cur][0];
    const _Float16* Bc = &Bs[cur][0];
    f16x8 af[4], bf[8];
    #pragma unroll
    for (int ri = 0; ri < 4; ++ri)
      af[ri] = *(const f16x8*)&Ac[swz_chunk(wr + ri * 16 + (lane & 15), lane >> 4) * 8];
    #pragma unroll
    for (int ci = 0; ci < 8; ++ci)
      bf[ci] = *(const f16x8*)&Bc[swz_chunk(wcc + ci * 16 + (lane & 15), lane >> 4) * 8];
    #pragma unroll
    for (int ri = 0; ri < 4; ++ri)
      #pragma unroll
      for (int ci = 0; ci < 8; ++ci)
        acc[ri][ci] = __builtin_amdgcn_mfma_f32_16x16x32_f16(af[ri], bf[ci], acc[ri][ci], 0, 0, 0);
    __syncthreads();
  }
  const int slab = ct;                 // C-tile = all 256 tokens of one slab
  #pragma unroll
  for (int ri = 0; ri < 4; ++ri) {
    #pragma unroll
    for (int ci = 0; ci < 8; ++ci) {
      int s = wcc + ci * 16 + (lane & 15);
      f32x4 v = acc[ri][ci];
      #pragma unroll
      for (int r = 0; r < 4; ++r) {
        int R = R0 + wr + ri * 16 + (lane >> 4) * 4 + r;
        out[((long)slab * DD + R) * SS + s] = v[r] + bo[R];
      }
    }
  }
}

// ---------------------------------------------------------------------------
// host launcher.  ws layout (~197 MiB):
//   [0)          A f16 [32768][768]  (reused as O after attention)
//   [50331648)   WQKV f16 [2304][768]
//   [53870592)   Wo   f16 [768][768]
//   [55050240)   upen f32 [32768]
//   [55181312)   Qp f16 [1024][12][32][64]
//   [105512960)  Kp f16  (same shape)
//   [155844608)  Vp f16  (same shape)   end 206176256
// ---------------------------------------------------------------------------
extern "C" void kernel_launch(void* const* d_in, const int* in_sizes, int n_in,
                              void* d_out, int out_size, void* d_ws, size_t ws_size,
                              hipStream_t stream) {
  const float* h   = (const float*)d_in[0];
  const float* u   = (const float*)d_in[1];
  const float* lam = (const float*)d_in[2];
  const float* Wq  = (const float*)d_in[3];
  const float* bq  = (const float*)d_in[4];
  const float* Wk  = (const float*)d_in[5];
  const float* bk  = (const float*)d_in[6];
  const float* Wv  = (const float*)d_in[7];
  const float* bv  = (const float*)d_in[8];
  const float* Wo  = (const float*)d_in[9];
  const float* bo  = (const float*)d_in[10];
  float* out = (float*)d_out;

  char* ws = (char*)d_ws;
  _Float16* Abuf = (_Float16*)(ws);
  _Float16* WQKV = (_Float16*)(ws + 50331648);
  _Float16* WoH  = (_Float16*)(ws + 53870592);
  float*    upen = (float*)   (ws + 55050240);
  _Float16* Qp   = (_Float16*)(ws + 55181312);
  _Float16* Kp   = (_Float16*)(ws + 105512960);
  _Float16* Vp   = (_Float16*)(ws + 155844608);

  hipMemsetAsync(upen, 0, 32768 * sizeof(float), stream);
  k_transpose_h<<<dim3(128, 12), 256, 0, stream>>>(h, Abuf);
  k_convert_w<<<1152, 256, 0, stream>>>(Wq, Wk, Wv, Wo, WQKV, WoH);
  k_upen<<<512, 256, 0, stream>>>(u, lam, upen);
  k_gemm_qkv<<<256 * 9, 256, 0, stream>>>(Abuf, WQKV, bq, bk, bv, Qp, Kp, Vp);
  k_attn<<<1024 * 3, 256, 0, stream>>>(Qp, Kp, Vp, upen, Abuf);
  k_gemm_out<<<128 * 6, 256, 0, stream>>>(WoH, Abuf, bo, out);
}

// Round 2
// 532.786 us; speedup vs baseline: 1.0194x; 1.0194x over previous
//
#include <hip/hip_runtime.h>

typedef float   f32x4 __attribute__((ext_vector_type(4)));
typedef _Float16 f16x8 __attribute__((ext_vector_type(8)));

#define DEV static __device__ __forceinline__

// ---- problem constants ----
#define BB 4
#define TT 32
#define DD 768
#define SS 256          // Hp*Wp
#define NHD 12
#define HD 64
#define NSEQ  (BB*SS)   // 1024 sequences
#define MTOK  (NSEQ*TT) // 32768 tokens

DEV void async_copy16(const _Float16* g, _Float16* l) {
  __builtin_amdgcn_global_load_lds(
      (const __attribute__((address_space(1))) unsigned int*)g,
      (__attribute__((address_space(3))) unsigned int*)l,
      16, 0, 0);
}

// XOR-swizzled LDS 16B-chunk index for [rows][4 chunk] tiles (BK=32 f16).
DEV int swz_chunk(int r, int kc) {
  return r * 4 + (kc ^ (r & 3) ^ ((r >> 2) & 3));
}

// ---------------------------------------------------------------------------
// K0a: h (B,T,D,Hp,Wp) fp32 -> A[token][d] f16  (d<->s transpose via LDS)
// ---------------------------------------------------------------------------
__global__ __launch_bounds__(256) void k_transpose_h(const float* __restrict__ h,
                                                     _Float16* __restrict__ A) {
  __shared__ _Float16 Tl[256 * 65];
  const int slab = blockIdx.x;
  const int d0   = blockIdx.y * 64;
  const int t    = threadIdx.x;
  const float4* hv = (const float4*)(h + (slab * DD + d0) * SS);
  #pragma unroll
  for (int i = 0; i < 16; ++i) {
    int dd = i * 4 + (t >> 6);
    int s4 = (t & 63) * 4;
    float4 v = hv[dd * 64 + (t & 63)];
    Tl[(s4 + 0) * 65 + dd] = (_Float16)v.x;
    Tl[(s4 + 1) * 65 + dd] = (_Float16)v.y;
    Tl[(s4 + 2) * 65 + dd] = (_Float16)v.z;
    Tl[(s4 + 3) * 65 + dd] = (_Float16)v.w;
  }
  __syncthreads();
  #pragma unroll
  for (int p = 0; p < 8; ++p) {
    int s  = p * 32 + (t >> 3);
    int dd = (t & 7) * 8;
    f16x8 val;
    #pragma unroll
    for (int j = 0; j < 8; ++j) val[j] = Tl[s * 65 + dd + j];
    *(f16x8*)(A + (slab * SS + s) * DD + d0 + dd) = val;
  }
}

// ---------------------------------------------------------------------------
// K0b: weights fp32 -> f16
// ---------------------------------------------------------------------------
__global__ __launch_bounds__(256) void k_convert_w(const float* __restrict__ Wq,
                                                   const float* __restrict__ Wk,
                                                   const float* __restrict__ Wv,
                                                   const float* __restrict__ Wo,
                                                   _Float16* __restrict__ WQKV,
                                                   _Float16* __restrict__ WoH) {
  int idx = blockIdx.x * 256 + threadIdx.x;
  int row = idx / 96;
  int c8  = (idx % 96) * 8;
  const float* src; _Float16* dst;
  if (row < 768)       { src = Wq + row * 768;          dst = WQKV + row * 768; }
  else if (row < 1536) { src = Wk + (row - 768) * 768;  dst = WQKV + row * 768; }
  else if (row < 2304) { src = Wv + (row - 1536) * 768; dst = WQKV + row * 768; }
  else                 { src = Wo + (row - 2304) * 768; dst = WoH  + (row - 2304) * 768; }
  float4 v0 = *(const float4*)(src + c8);
  float4 v1 = *(const float4*)(src + c8 + 4);
  f16x8 o;
  o[0]=(_Float16)v0.x; o[1]=(_Float16)v0.y; o[2]=(_Float16)v0.z; o[3]=(_Float16)v0.w;
  o[4]=(_Float16)v1.x; o[5]=(_Float16)v1.y; o[6]=(_Float16)v1.z; o[7]=(_Float16)v1.w;
  *(f16x8*)(dst + c8) = o;
}

// ---------------------------------------------------------------------------
// K1: u_pen[(b*256+s)*32 + t] = lam * mean_d u
// ---------------------------------------------------------------------------
__global__ __launch_bounds__(256) void k_upen(const float* __restrict__ u,
                                              const float* __restrict__ lam,
                                              float* __restrict__ upen) {
  int slab = blockIdx.x >> 2;
  int q    = blockIdx.x & 3;
  int s    = threadIdx.x;
  const float* base = u + (slab * DD + q * 192) * SS + s;
  float sum = 0.f;
  for (int d = 0; d < 192; ++d) sum += base[d * SS];
  int b = slab >> 5, tt = slab & 31;
  float l = lam[slab * SS + s];
  atomicAdd(&upen[(b * SS + s) * TT + tt], sum * l * (1.0f / 768.0f));
}

// ---------------------------------------------------------------------------
// K2 v4: QKV GEMM, 256x256 tile, BK=64, 512 thr = 8 waves (2M x 4N).
// Phase-split schedule (port of the 8-phase template, 4 phases per K-tile):
//   phase = { ds_read reg subtile [+ stage-issue] ; s_barrier ;
//             lgkmcnt(0)+sched_barrier ; setprio(1) ; 16 MFMA ; setprio(0) ;
//             s_barrier }
// Staging for tile t+1 issued at phases 0/1 (global_load_lds x8, pre-swizzled
// source so linear LDS dest yields XOR-swizzled layout); single counted drain
// (vmcnt(0), ~3 phases after issue) at iter end. LDS 128KB dbuf.
// ds_read pattern: slot = kc ^ (row&7) -> 2 rows/bank-quad = conflict-free.
// Epilogue writes packed Qp/Kp/Vp[seq][head][t][hd], Q scaled by 1/8.
// Grid: XCD-chunked swizzle, 9 nt-variants of same mt adjacent (A L2 reuse).
// ---------------------------------------------------------------------------
__global__ __launch_bounds__(512, 2) void k_gemm_qkv(const _Float16* __restrict__ A,
                                                     const _Float16* __restrict__ Bw,
                                                     const float* __restrict__ bq,
                                                     const float* __restrict__ bk,
                                                     const float* __restrict__ bv,
                                                     _Float16* __restrict__ Qp,
                                                     _Float16* __restrict__ Kp,
                                                     _Float16* __restrict__ Vp) {
  __shared__ __align__(16) _Float16 As[2][256 * 64];   // 32KB per buf
  __shared__ __align__(16) _Float16 Bs[2][256 * 64];   // 32KB per buf
  const int swz = (blockIdx.x & 7) * 144 + (blockIdx.x >> 3);   // 1152 = 8*144
  const int mt = swz / 9, nt = swz - mt * 9;
  const int m0 = mt * 256, n0 = nt * 256;
  const int tid = threadIdx.x, lane = tid & 63, w = tid >> 6;
  const int wm = w >> 2, wn = w & 3;       // wave rows wm*128.., cols wn*64..
  f32x4 acc[8][4] = {};

  auto stage = [&](const _Float16* __restrict__ g, int grow0, _Float16* l, int k0) {
    #pragma unroll
    for (int li = 0; li < 4; ++li) {
      int cc = tid + 512 * li;             // 16B chunk id, lane-linear
      int row = cc >> 3;                   // 8 chunks per 64-f16 row
      int kc = (cc & 7) ^ (row & 7);       // inverse swizzle on SOURCE
      async_copy16(g + (grow0 + row) * DD + k0 + kc * 8, l + cc * 8);
    }
  };

  stage(A, m0, &As[0][0], 0);
  stage(Bw, n0, &Bs[0][0], 0);
  __syncthreads();                         // drains vmcnt(0): buf0 ready

  for (int it = 0; it < 12; ++it) {
    const int cb = it & 1;
    const _Float16* Ac = &As[cb][0];
    const _Float16* Bc = &Bs[cb][0];
    const int kn = (it + 1) * 64;
    f16x8 bfr[4][2];
    #pragma unroll
    for (int p = 0; p < 4; ++p) {
      f16x8 afr[2][2];
      #pragma unroll
      for (int q = 0; q < 2; ++q)
        #pragma unroll
        for (int kk = 0; kk < 2; ++kk) {
          int row = wm * 128 + (2 * p + q) * 16 + (lane & 15);
          int kc = kk * 4 + (lane >> 4);
          afr[q][kk] = *(const f16x8*)&Ac[row * 64 + (kc ^ (row & 7)) * 8];
        }
      if (p == 0) {
        #pragma unroll
        for (int ni = 0; ni < 4; ++ni)
          #pragma unroll
          for (int kk = 0; kk < 2; ++kk) {
            int row = wn * 64 + ni * 16 + (lane & 15);
            int kc = kk * 4 + (lane >> 4);
            bfr[ni][kk] = *(const f16x8*)&Bc[row * 64 + (kc ^ (row & 7)) * 8];
          }
        if (it < 11) stage(A, m0, &As[cb ^ 1][0], kn);
      }
      if (p == 1 && it < 11) stage(Bw, n0, &Bs[cb ^ 1][0], kn);
      __builtin_amdgcn_s_barrier();
      asm volatile("s_waitcnt lgkmcnt(0)" ::: "memory");
      __builtin_amdgcn_sched_barrier(0);
      __builtin_amdgcn_s_setprio(1);
      #pragma unroll
      for (int q = 0; q < 2; ++q)
        #pragma unroll
        for (int ni = 0; ni < 4; ++ni) {
          acc[2 * p + q][ni] = __builtin_amdgcn_mfma_f32_16x16x32_f16(
              afr[q][0], bfr[ni][0], acc[2 * p + q][ni], 0, 0, 0);
          acc[2 * p + q][ni] = __builtin_amdgcn_mfma_f32_16x16x32_f16(
              afr[q][1], bfr[ni][1], acc[2 * p + q][ni], 0, 0, 0);
        }
      __builtin_amdgcn_s_setprio(0);
      __builtin_amdgcn_s_barrier();
    }
    // counted drain, once per K-tile: loads issued >=2 phases ago
    asm volatile("s_waitcnt vmcnt(0)" ::: "memory");
    __builtin_amdgcn_sched_barrier(0);
    __builtin_amdgcn_s_barrier();
  }

  // epilogue: n -> (sel, head, hd); m -> (b, t, s); packed [seq][head][t][hd]
  const int sel = nt / 3;                                   // 0=Q 1=K 2=V
  const float scale = (sel == 0) ? 0.125f : 1.0f;           // fold 1/sqrt(64)
  const float* bias = (sel == 0) ? bq : ((sel == 1) ? bk : bv);
  _Float16* dst = (sel == 0) ? Qp : ((sel == 1) ? Kp : Vp);
  const int b = mt >> 5, t = mt & 31;
  #pragma unroll
  for (int ni = 0; ni < 4; ++ni) {
    int n768 = nt * 256 - sel * 768 + wn * 64 + ni * 16 + (lane & 15);
    int head = n768 >> 6, hd = n768 & 63;
    float bs = bias[n768];
    long hb = (long)head * 2048 + t * 64 + hd;
    #pragma unroll
    for (int mi = 0; mi < 8; ++mi) {
      f32x4 v = acc[mi][ni];
      #pragma unroll
      for (int r = 0; r < 4; ++r) {
        int s = wm * 128 + mi * 16 + (lane >> 4) * 4 + r;
        long seq = (long)b * 256 + s;
        dst[seq * 24576 + hb] = (_Float16)((v[r] + bs) * scale);
      }
    }
  }
}

// ---------------------------------------------------------------------------
// K3: attention v2. 1 wave per (seq, head); all global reads dense 4KB blocks.
// V transposed through per-wave LDS (stride 66: both sides 2-way = free).
// O written token-major into Abuf for the output GEMM.
// ---------------------------------------------------------------------------
__global__ __launch_bounds__(256) void k_attn(const _Float16* __restrict__ Qp,
                                              const _Float16* __restrict__ Kp,
                                              const _Float16* __restrict__ Vp,
                                              const float* __restrict__ upen,
                                              _Float16* __restrict__ O) {
  __shared__ _Float16 lds[4][32 * 66 + 32 * 40];   // per-wave: Vs[32][66], Ps[32][40]
  const int w = threadIdx.x >> 6, lane = threadIdx.x & 63;
  const int seq = blockIdx.x / 3, hg = blockIdx.x % 3;
  const int head = hg * 4 + w;
  const int b = seq >> 8, s = seq & 255;
  _Float16* Vs = &lds[w][0];
  _Float16* Ps = &lds[w][32 * 66];
  const long base = (long)(seq * NHD + head) * 2048;
  const _Float16* Qb = Qp + base;
  const _Float16* Kb = Kp + base;
  const _Float16* Vb = Vp + base;

  // stage V (dense 4KB) -> LDS stride 66, f16x2 writes (2-way, free)
  {
    int t = lane & 31, hh = (lane >> 5) * 32;
    f16x8 vc[4];
    #pragma unroll
    for (int c = 0; c < 4; ++c) vc[c] = *(const f16x8*)(Vb + t * 64 + hh + c * 8);
    #pragma unroll
    for (int c = 0; c < 4; ++c)
      #pragma unroll
      for (int p = 0; p < 4; ++p) {
        union { _Float16 h[2]; unsigned u; } pk;
        pk.h[0] = vc[c][2 * p]; pk.h[1] = vc[c][2 * p + 1];
        *(unsigned*)&Vs[t * 66 + hh + c * 8 + 2 * p] = pk.u;
      }
  }
  // Q/K fragments direct from global (dense within the 4KB block)
  f16x8 qf[2][2], kf[2][2];
  #pragma unroll
  for (int i = 0; i < 2; ++i)
    #pragma unroll
    for (int ks = 0; ks < 2; ++ks) {
      int off = (i * 16 + (lane & 15)) * 64 + ks * 32 + (lane >> 4) * 8;
      qf[i][ks] = *(const f16x8*)(Qb + off);
      kf[i][ks] = *(const f16x8*)(Kb + off);
    }
  // scores = (Q/8) . K^T
  f32x4 sc[2][2] = {};
  #pragma unroll
  for (int mq = 0; mq < 2; ++mq)
    #pragma unroll
    for (int nk = 0; nk < 2; ++nk)
      #pragma unroll
      for (int ks = 0; ks < 2; ++ks)
        sc[mq][nk] = __builtin_amdgcn_mfma_f32_16x16x32_f16(qf[mq][ks], kf[nk][ks], sc[mq][nk], 0, 0, 0);

  const float up0 = upen[seq * TT + (lane & 15)];
  const float up1 = upen[seq * TT + 16 + (lane & 15)];

  // softmax over 32 keys per query row
  #pragma unroll
  for (int mq = 0; mq < 2; ++mq) {
    #pragma unroll
    for (int r = 0; r < 4; ++r) {
      float s0 = sc[mq][0][r] - up0;
      float s1 = sc[mq][1][r] - up1;
      float mx = fmaxf(s0, s1);
      #pragma unroll
      for (int off = 1; off < 16; off <<= 1) mx = fmaxf(mx, __shfl_xor(mx, off, 64));
      float e0 = __expf(s0 - mx), e1 = __expf(s1 - mx);
      float sum = e0 + e1;
      #pragma unroll
      for (int off = 1; off < 16; off <<= 1) sum += __shfl_xor(sum, off, 64);
      float inv = 1.0f / sum;
      int row = mq * 16 + (lane >> 4) * 4 + r;
      Ps[row * 40 + (lane & 15)]      = (_Float16)(e0 * inv);
      Ps[row * 40 + 16 + (lane & 15)] = (_Float16)(e1 * inv);
    }
  }
  // PV
  f16x8 pf[2];
  #pragma unroll
  for (int mq = 0; mq < 2; ++mq)
    pf[mq] = *(const f16x8*)(Ps + (mq * 16 + (lane & 15)) * 40 + (lane >> 4) * 8);
  f32x4 oacc[2][4] = {};
  #pragma unroll
  for (int nh = 0; nh < 4; ++nh) {
    int hd = nh * 16 + (lane & 15);
    f16x8 vf;
    #pragma unroll
    for (int j = 0; j < 8; ++j) vf[j] = Vs[((lane >> 4) * 8 + j) * 66 + hd];  // 2-way, free
    #pragma unroll
    for (int mq = 0; mq < 2; ++mq)
      oacc[mq][nh] = __builtin_amdgcn_mfma_f32_16x16x32_f16(pf[mq], vf, oacc[mq][nh], 0, 0, 0);
  }
  // write O token-major [m][768]
  #pragma unroll
  for (int mq = 0; mq < 2; ++mq)
    #pragma unroll
    for (int nh = 0; nh < 4; ++nh) {
      int hd = nh * 16 + (lane & 15);
      #pragma unroll
      for (int r = 0; r < 4; ++r) {
        int t = mq * 16 + (lane >> 4) * 4 + r;
        O[((long)((b << 5) + t) * SS + s) * DD + head * HD + hd] = (_Float16)oacc[mq][nh][r];
      }
    }
}

// ---------------------------------------------------------------------------
// K4: output GEMM, swapped operands: C'[R][token] = Wo[R][:] . O[token][:]
// Block tile 128R x 256tok, 4 waves of 64x128. ct-fastest for XCD locality.
// Writes final (B,T,D,Hp,Wp) fp32 with s-contiguous coalesced stores.
// ---------------------------------------------------------------------------
__global__ __launch_bounds__(256, 2) void k_gemm_out(const _Float16* __restrict__ Wn,
                                                     const _Float16* __restrict__ O,
                                                     const float* __restrict__ bo,
                                                     float* __restrict__ out) {
  __shared__ _Float16 As[128 * 32];   // Wo rows
  __shared__ _Float16 Bs[256 * 32];   // O token rows
  const int ct = blockIdx.x & 127, rt = blockIdx.x >> 7;   // ct-fastest
  const int R0 = rt * 128, C0 = ct * 256;
  const int tid = threadIdx.x, w = tid >> 6, lane = tid & 63;
  const int wr = (w >> 1) * 64, wcc = (w & 1) * 128;
  f32x4 acc[4][8] = {};
  for (int it = 0; it < 24; ++it) {
    const int k0 = it * 32;
    __syncthreads();
    #pragma unroll
    for (int i = 0; i < 2; ++i) {
      int c = tid + 256 * i;
      int row = c >> 2;
      int coff = ((c & 3) ^ (row & 3) ^ ((row >> 2) & 3)) * 8;
      _Float16* ldsA = (_Float16*)((char*)As + (w * 1024 + i * 4096 + lane * 16));
      async_copy16(Wn + (R0 + row) * DD + k0 + coff, ldsA);
    }
    #pragma unroll
    for (int i = 0; i < 4; ++i) {
      int c = tid + 256 * i;
      int row = c >> 2;
      int coff = ((c & 3) ^ (row & 3) ^ ((row >> 2) & 3)) * 8;
      _Float16* ldsB = (_Float16*)((char*)Bs + (w * 1024 + i * 4096 + lane * 16));
      async_copy16(O + (C0 + row) * DD + k0 + coff, ldsB);
    }
    __syncthreads();
    f16x8 af[4], bf[8];
    #pragma unroll
    for (int ri = 0; ri < 4; ++ri)
      af[ri] = *(const f16x8*)&As[swz_chunk(wr + ri * 16 + (lane & 15), lane >> 4) * 8];
    #pragma unroll
    for (int ci = 0; ci < 8; ++ci)
      bf[ci] = *(const f16x8*)&Bs[swz_chunk(wcc + ci * 16 + (lane & 15), lane >> 4) * 8];
    #pragma unroll
    for (int ri = 0; ri < 4; ++ri)
      #pragma unroll
      for (int ci = 0; ci < 8; ++ci)
        acc[ri][ci] = __builtin_amdgcn_mfma_f32_16x16x32_f16(af[ri], bf[ci], acc[ri][ci], 0, 0, 0);
  }
  const int slab = ct;                 // C-tile = all 256 tokens of one slab
  #pragma unroll
  for (int ri = 0; ri < 4; ++ri) {
    #pragma unroll
    for (int ci = 0; ci < 8; ++ci) {
      int s = wcc + ci * 16 + (lane & 15);
      f32x4 v = acc[ri][ci];
      #pragma unroll
      for (int r = 0; r < 4; ++r) {
        int R = R0 + wr + ri * 16 + (lane >> 4) * 4 + r;
        out[((long)slab * DD + R) * SS + s] = v[r] + bo[R];
      }
    }
  }
}

// ---------------------------------------------------------------------------
// host launcher.  ws layout (~197 MiB):
//   [0)          A f16 [32768][768]  (reused as O after attention)
//   [50331648)   WQKV f16 [2304][768]
//   [53870592)   Wo   f16 [768][768]
//   [55050240)   upen f32 [32768]
//   [55181312)   Qp f16 [1024][12][32][64]
//   [105512960)  Kp f16  (same shape)
//   [155844608)  Vp f16  (same shape)   end 206176256
// ---------------------------------------------------------------------------
extern "C" void kernel_launch(void* const* d_in, const int* in_sizes, int n_in,
                              void* d_out, int out_size, void* d_ws, size_t ws_size,
                              hipStream_t stream) {
  const float* h   = (const float*)d_in[0];
  const float* u   = (const float*)d_in[1];
  const float* lam = (const float*)d_in[2];
  const float* Wq  = (const float*)d_in[3];
  const float* bq  = (const float*)d_in[4];
  const float* Wk  = (const float*)d_in[5];
  const float* bk  = (const float*)d_in[6];
  const float* Wv  = (const float*)d_in[7];
  const float* bv  = (const float*)d_in[8];
  const float* Wo  = (const float*)d_in[9];
  const float* bo  = (const float*)d_in[10];
  float* out = (float*)d_out;

  char* ws = (char*)d_ws;
  _Float16* Abuf = (_Float16*)(ws);
  _Float16* WQKV = (_Float16*)(ws + 50331648);
  _Float16* WoH  = (_Float16*)(ws + 53870592);
  float*    upen = (float*)   (ws + 55050240);
  _Float16* Qp   = (_Float16*)(ws + 55181312);
  _Float16* Kp   = (_Float16*)(ws + 105512960);
  _Float16* Vp   = (_Float16*)(ws + 155844608);

  hipMemsetAsync(upen, 0, 32768 * sizeof(float), stream);
  k_transpose_h<<<dim3(128, 12), 256, 0, stream>>>(h, Abuf);
  k_convert_w<<<1152, 256, 0, stream>>>(Wq, Wk, Wv, Wo, WQKV, WoH);
  k_upen<<<512, 256, 0, stream>>>(u, lam, upen);
  k_gemm_qkv<<<1152, 512, 0, stream>>>(Abuf, WQKV, bq, bk, bv, Qp, Kp, Vp);
  k_attn<<<1024 * 3, 256, 0, stream>>>(Qp, Kp, Vp, upen, Abuf);
  k_gemm_out<<<128 * 6, 256, 0, stream>>>(WoH, Abuf, bo, out);
}